// Round 3
// baseline (429.823 us; speedup 1.0000x reference)
//
#include <hip/hip_runtime.h>

typedef unsigned short u16;
typedef __bf16 bf16x8 __attribute__((ext_vector_type(8)));
typedef float f32x4 __attribute__((ext_vector_type(4)));

#define MFMA(a, b, c) __builtin_amdgcn_mfma_f32_16x16x32_bf16(a, b, c, 0, 0, 0)

// Constants: B=4, H=64, W=128, D=128, NS=2, hh=32, ww=64, sh=16, sw=32,
// L=2048, 16 windows, 32768 rows total.

__device__ __forceinline__ u16 f2b(float f) {
  unsigned u = __builtin_bit_cast(unsigned, f);
  u += 0x7fffu + ((u >> 16) & 1u);
  return (u16)(u >> 16);
}

// ---------------- workspace layout (bytes) ----------------
// qw 0..8M, kw 8..16M, vbuf 16..24M, o1 24..40M (fp32), o2 40..56M (fp32)
// hid 0..64M (after wmln; overlaps dead attn buffers)
// srcb 64..72M, msg1 72..80M, l1/l2 @80M (128KB each), weights @80M+256K
#define QW_OFF   ((size_t)0)
#define KW_OFF   ((size_t)8 << 20)
#define VBUF_OFF ((size_t)16 << 20)
#define O1_OFF   ((size_t)24 << 20)
#define O2_OFF   ((size_t)40 << 20)
#define HID_OFF  ((size_t)0)
#define SRCB_OFF ((size_t)64 << 20)
#define MSG1_OFF ((size_t)72 << 20)
#define L1_OFF   ((size_t)80 << 20)
#define L2P_OFF  (((size_t)80 << 20) + 131072)
#define WQT_OFF  (((size_t)80 << 20) + 262144)
#define WKT_OFF  (WQT_OFF + 32768)
#define WVT_OFF  (WQT_OFF + 65536)
#define WMT_OFF  (WQT_OFF + 98304)
#define W1T_OFF  (WQT_OFF + 131072)   // 1024x256 bf16 = 512KB
#define W2T_OFF  (WQT_OFF + 655360)   // 128x1024 bf16 = 256KB

// ---------------- kernel 0: transpose weights to bf16 [n][k]; scale folded into Wq ----
__global__ void k_prep(const float* __restrict__ wq, const float* __restrict__ wk,
                       const float* __restrict__ wv, const float* __restrict__ wm,
                       const float* __restrict__ w1, const float* __restrict__ w2,
                       u16* __restrict__ wqt, u16* __restrict__ wkt,
                       u16* __restrict__ wvt, u16* __restrict__ wmt,
                       u16* __restrict__ w1t, u16* __restrict__ w2t) {
  int t = blockIdx.x * 256 + threadIdx.x;
  if (t < 65536) {
    int m = t >> 14, loc = t & 16383;
    int n = loc >> 7, k = loc & 127;
    const float* s = (m == 0) ? wq : (m == 1) ? wk : (m == 2) ? wv : wm;
    u16* d = (m == 0) ? wqt : (m == 1) ? wkt : (m == 2) ? wvt : wmt;
    const float sc = (m == 0) ? 0.08838834764831845f : 1.0f;  // 1/sqrt(128) into Wq
    d[n * 128 + k] = f2b(s[k * 128 + n] * sc);
  } else if (t < 65536 + 262144) {
    int loc = t - 65536;
    int n = loc >> 8, k = loc & 255;            // W1: (256,1024) -> [n][k=256]
    w1t[n * 256 + k] = f2b(w1[k * 1024 + n]);
  } else if (t < 65536 + 262144 + 131072) {
    int loc = t - 327680;
    int n = loc >> 10, k = loc & 1023;          // W2: (1024,128) -> [n][k=1024]
    w2t[n * 1024 + k] = f2b(w2[k * 128 + n]);
  }
}

// ---------------- kernel 1: QKV projection (LDS-free), scatter to window layout ------
// qw/kw: [g][p][d] bf16.  vbuf: [g][d][p] bf16 (transposed for PV B-operand).
__global__ void k_qkv(const float* __restrict__ src,
                      const u16* __restrict__ wtq, const u16* __restrict__ wtk,
                      const u16* __restrict__ wtv,
                      u16* __restrict__ qw, u16* __restrict__ kw,
                      u16* __restrict__ vbuf, u16* __restrict__ srcb) {
  const int tid = threadIdx.x, bid = blockIdx.x;
  const int lane = tid & 63, wid = tid >> 6;
  const int l15 = lane & 15, quad = lane >> 4;

  // this lane's A-row (window-order token)
  const int t = bid * 64 + wid * 16 + l15;
  const int g = t >> 11, p = t & 2047;
  const int b = g >> 2, wi = (g >> 1) & 1, wj = g & 1;
  const int ii = p >> 6, jj = p & 63;
  const int y = (wi * 32 + ii + 16) & 63;
  const int x = (wj * 64 + jj + 32) & 127;
  const int srow = b * 8192 + y * 128 + x;

  bf16x8 afrag[4];
#pragma unroll
  for (int kk = 0; kk < 4; ++kk) {
    const float* sp = src + srow * 128 + kk * 32 + quad * 8;
    float4 v0 = *(const float4*)sp, v1 = *(const float4*)(sp + 4);
    union { bf16x8 v; ushort4 h[2]; uint4 q; } u;
    u.h[0] = make_ushort4(f2b(v0.x), f2b(v0.y), f2b(v0.z), f2b(v0.w));
    u.h[1] = make_ushort4(f2b(v1.x), f2b(v1.y), f2b(v1.z), f2b(v1.w));
    afrag[kk] = u.v;
    *(uint4*)(srcb + srow * 128 + kk * 32 + quad * 8) = u.q;   // bf16 source copy
  }

  const f32x4 fz = {0.f, 0.f, 0.f, 0.f};
  const int t0 = bid * 64 + wid * 16 + quad * 4;
#pragma unroll 1
  for (int m = 0; m < 3; ++m) {
    const u16* wp = (m == 0) ? wtq : (m == 1) ? wtk : wtv;
    f32x4 acc[8];
#pragma unroll
    for (int nt = 0; nt < 8; ++nt) acc[nt] = fz;
#pragma unroll
    for (int kk = 0; kk < 4; ++kk)
#pragma unroll
      for (int nt = 0; nt < 8; ++nt) {
        bf16x8 bfr = *(const bf16x8*)(wp + (nt * 16 + l15) * 128 + kk * 32 + quad * 8);
        acc[nt] = MFMA(afrag[kk], bfr, acc[nt]);
      }
    if (m < 2) {
      u16* dst = (m == 0) ? qw : kw;
#pragma unroll
      for (int nt = 0; nt < 8; ++nt) {
        const int d = nt * 16 + l15;
#pragma unroll
        for (int r = 0; r < 4; ++r) dst[(t0 + r) * 128 + d] = f2b(acc[nt][r]);
      }
    } else {
      const int gg = bid >> 5;
      const int p0 = t0 & 2047;
#pragma unroll
      for (int nt = 0; nt < 8; ++nt) {
        const int d = nt * 16 + l15;
        ushort4 hv = make_ushort4(f2b(acc[nt][0]), f2b(acc[nt][1]),
                                  f2b(acc[nt][2]), f2b(acc[nt][3]));
        *(ushort4*)&vbuf[gg * 262144 + d * 2048 + p0] = hv;
      }
    }
  }
}

// ---------------- kernel 2: attention, split-K x2, fixed-max softmax -----------------
// bid = (g*2 + half)*32 + qb. Writes unnormalized O partial (fp32, window-order rows)
// and l partial. Q is pre-scaled (Wq); mask used as MFMA C-initializer.
__global__ __launch_bounds__(256, 3)
void k_attn(const u16* __restrict__ qw, const u16* __restrict__ kw,
            const u16* __restrict__ vbuf, const float* __restrict__ mask,
            float* __restrict__ o1, float* __restrict__ o2,
            float* __restrict__ l1, float* __restrict__ l2) {
  __shared__ __align__(16) u16 Kt[64 * 136];
  __shared__ __align__(16) u16 Vt[128 * 72];
  __shared__ __align__(16) u16 Pt[64 * 72];
  const int tid = threadIdx.x, bid = blockIdx.x;
  const int lane = tid & 63, wid = tid >> 6;
  const int l15 = lane & 15, quad = lane >> 4;
  const int g = bid >> 6, half = (bid >> 5) & 1, qb = bid & 31;
  const int k0 = half * 1024;
  const u16* kbase = kw + g * 262144 + k0 * 128;
  const u16* vbase = vbuf + g * 262144 + k0;
  const int qrow0 = qb * 64 + wid * 16 + quad * 4;   // window-local q row
  const float* mrow = mask + (size_t)(g & 3) * 4194304 + (size_t)qrow0 * 2048 + k0;

  bf16x8 qfrag[4];
  {
    const u16* qp = qw + g * 262144 + (qb * 64 + wid * 16 + l15) * 128 + quad * 8;
#pragma unroll
    for (int kk = 0; kk < 4; ++kk) qfrag[kk] = *(const bf16x8*)(qp + kk * 32);
  }
  const f32x4 fz = {0.f, 0.f, 0.f, 0.f};
  f32x4 o[8];
#pragma unroll
  for (int nt = 0; nt < 8; ++nt) o[nt] = fz;
  float lr[4] = {0.f, 0.f, 0.f, 0.f};
  const float L2E = 1.4426950408889634f;

#pragma unroll 1
  for (int kt = 0; kt < 16; ++kt) {
    __syncthreads();
    {  // stage K tile [key][d]
      const int row = tid >> 2, part = tid & 3;
      const uint4* sp = (const uint4*)(kbase + (kt * 64 + row) * 128 + part * 32);
      uint4* dp = (uint4*)&Kt[row * 136 + part * 32];
#pragma unroll
      for (int q = 0; q < 4; ++q) dp[q] = sp[q];
    }
    {  // stage V tile transposed [d][key]
      const int dd = tid >> 1, h2 = tid & 1;
      const uint4* sp = (const uint4*)(vbase + dd * 2048 + kt * 64 + h2 * 32);
      uint4* dp = (uint4*)&Vt[dd * 72 + h2 * 32];
#pragma unroll
      for (int q = 0; q < 4; ++q) dp[q] = sp[q];
    }
    __syncthreads();

    // S = Q K^T + mask (mask preloaded as accumulator init; Q pre-scaled)
    f32x4 s[4];
#pragma unroll
    for (int nt = 0; nt < 4; ++nt) {
      const int kc = kt * 64 + nt * 16 + l15;
#pragma unroll
      for (int r = 0; r < 4; ++r) s[nt][r] = mrow[r * 2048 + kc];
    }
#pragma unroll
    for (int kk = 0; kk < 4; ++kk)
#pragma unroll
      for (int nt = 0; nt < 4; ++nt) {
        bf16x8 bfr = *(const bf16x8*)&Kt[(nt * 16 + l15) * 136 + kk * 32 + quad * 8];
        s[nt] = MFMA(qfrag[kk], bfr, s[nt]);
      }
    // fixed-max softmax: p = e^s, row-sum into lr
    float rs[4] = {0.f, 0.f, 0.f, 0.f};
#pragma unroll
    for (int nt = 0; nt < 4; ++nt)
#pragma unroll
      for (int r = 0; r < 4; ++r) {
        const float pv = exp2f(s[nt][r] * L2E);
        rs[r] += pv;
        Pt[(wid * 16 + quad * 4 + r) * 72 + nt * 16 + l15] = f2b(pv);
      }
#pragma unroll
    for (int off = 1; off < 16; off <<= 1)
#pragma unroll
      for (int r = 0; r < 4; ++r) rs[r] += __shfl_xor(rs[r], off, 16);
#pragma unroll
    for (int r = 0; r < 4; ++r) lr[r] += rs[r];

    // O += P @ V (P via per-wave LDS round-trip, C-layout -> A-layout)
    bf16x8 pfrag[2];
#pragma unroll
    for (int kk = 0; kk < 2; ++kk)
      pfrag[kk] = *(const bf16x8*)&Pt[(wid * 16 + l15) * 72 + kk * 32 + quad * 8];
#pragma unroll
    for (int nt = 0; nt < 8; ++nt)
#pragma unroll
      for (int kk = 0; kk < 2; ++kk) {
        bf16x8 bfr = *(const bf16x8*)&Vt[(nt * 16 + l15) * 72 + kk * 32 + quad * 8];
        o[nt] = MFMA(pfrag[kk], bfr, o[nt]);
      }
  }

  float* op = half ? o2 : o1;
  float* lp = half ? l2 : l1;
  const int t0 = g * 2048 + qrow0;
#pragma unroll
  for (int nt = 0; nt < 8; ++nt)
#pragma unroll
    for (int r = 0; r < 4; ++r)
      op[(size_t)(t0 + r) * 128 + nt * 16 + l15] = o[nt][r];
  if (l15 == 0)
#pragma unroll
    for (int r = 0; r < 4; ++r) lp[t0 + r] = lr[r];
}

// ---------------- kernel 3: merge partials + @Wm + LN(g1,b1) -> msg1 (spatial) -------
__global__ __launch_bounds__(256, 4)
void k_wmln(const float* __restrict__ o1, const float* __restrict__ o2,
            const float* __restrict__ l1, const float* __restrict__ l2,
            const u16* __restrict__ wmt, const float* __restrict__ g1,
            const float* __restrict__ b1, u16* __restrict__ msg1) {
  const int tid = threadIdx.x, bid = blockIdx.x;
  const int lane = tid & 63, wid = tid >> 6;
  const int l15 = lane & 15, quad = lane >> 4;
  const int m = bid * 64 + wid * 16 + l15;       // window-order row
  const float linv = 1.f / (l1[m] + l2[m]);

  bf16x8 afrag[4];
#pragma unroll
  for (int kk = 0; kk < 4; ++kk) {
    const float* p1 = o1 + (size_t)m * 128 + kk * 32 + quad * 8;
    const float* p2 = o2 + (size_t)m * 128 + kk * 32 + quad * 8;
    float4 a0 = *(const float4*)p1, a1 = *(const float4*)(p1 + 4);
    float4 c0 = *(const float4*)p2, c1 = *(const float4*)(p2 + 4);
    union { bf16x8 v; ushort4 h[2]; } u;
    u.h[0] = make_ushort4(f2b((a0.x + c0.x) * linv), f2b((a0.y + c0.y) * linv),
                          f2b((a0.z + c0.z) * linv), f2b((a0.w + c0.w) * linv));
    u.h[1] = make_ushort4(f2b((a1.x + c1.x) * linv), f2b((a1.y + c1.y) * linv),
                          f2b((a1.z + c1.z) * linv), f2b((a1.w + c1.w) * linv));
    afrag[kk] = u.v;
  }
  const f32x4 fz = {0.f, 0.f, 0.f, 0.f};
  f32x4 acc[8];
#pragma unroll
  for (int nt = 0; nt < 8; ++nt) acc[nt] = fz;
#pragma unroll
  for (int kk = 0; kk < 4; ++kk)
#pragma unroll
    for (int nt = 0; nt < 8; ++nt) {
      bf16x8 bfr = *(const bf16x8*)(wmt + (nt * 16 + l15) * 128 + kk * 32 + quad * 8);
      acc[nt] = MFMA(afrag[kk], bfr, acc[nt]);
    }
  float sum[4] = {0, 0, 0, 0}, sq[4] = {0, 0, 0, 0};
#pragma unroll
  for (int nt = 0; nt < 8; ++nt)
#pragma unroll
    for (int r = 0; r < 4; ++r) {
      const float v = acc[nt][r];
      sum[r] += v;
      sq[r] += v * v;
    }
#pragma unroll
  for (int off = 1; off < 16; off <<= 1)
#pragma unroll
    for (int r = 0; r < 4; ++r) {
      sum[r] += __shfl_xor(sum[r], off, 16);
      sq[r] += __shfl_xor(sq[r], off, 16);
    }
  float mean[4], rstd[4];
#pragma unroll
  for (int r = 0; r < 4; ++r) {
    mean[r] = sum[r] * (1.f / 128.f);
    const float var = sq[r] * (1.f / 128.f) - mean[r] * mean[r];
    rstd[r] = rsqrtf(var + 1e-5f);
  }
  const int t0 = bid * 64 + wid * 16 + quad * 4;
#pragma unroll
  for (int nt = 0; nt < 8; ++nt) {
    const int d = nt * 16 + l15;
    const float gg = g1[d], bb = b1[d];
#pragma unroll
    for (int r = 0; r < 4; ++r) {
      const int tt = t0 + r;                     // window-order -> spatial scatter
      const int gw = tt >> 11, pp = tt & 2047;
      const int bb2 = gw >> 2, wi = (gw >> 1) & 1, wj = gw & 1;
      const int ii = pp >> 6, jj = pp & 63;
      const int yy = (wi * 32 + ii + 16) & 63;
      const int xx = (wj * 64 + jj + 32) & 127;
      msg1[(bb2 * 8192 + yy * 128 + xx) * 128 + d] =
          f2b((acc[nt][r] - mean[r]) * rstd[r] * gg + bb);
    }
  }
}

// ---------------- kernel 4: gelu([src||msg1] @ W1) -> hidden bf16 --------------------
__global__ __launch_bounds__(256, 3)
void k_mlp1(const u16* __restrict__ srcb, const u16* __restrict__ msg1,
            const u16* __restrict__ w1t, u16* __restrict__ hid) {
  __shared__ __align__(16) u16 Bt[256 * 72];
  const int tid = threadIdx.x, bid = blockIdx.x;
  const int rb = bid >> 2, nb = bid & 3;
  const int lane = tid & 63, wid = tid >> 6;
  const int l15 = lane & 15, quad = lane >> 4;
  const int arow = rb * 64 + wid * 16 + l15;
  const f32x4 fz = {0.f, 0.f, 0.f, 0.f};
  f32x4 acc[16];
#pragma unroll
  for (int nt = 0; nt < 16; ++nt) acc[nt] = fz;
#pragma unroll 1
  for (int kc = 0; kc < 4; ++kc) {  // K chunks: src[0:64],src[64:128],msg[0:64],msg[64:128]
    __syncthreads();
    {
      const uint4* sp = (const uint4*)(w1t + (nb * 256 + tid) * 256 + kc * 64);
      uint4* dp = (uint4*)&Bt[tid * 72];
#pragma unroll
      for (int q = 0; q < 8; ++q) dp[q] = sp[q];
    }
    __syncthreads();
    const u16* ab = (kc < 2 ? srcb : msg1) + arow * 128 + (kc & 1) * 64;
#pragma unroll
    for (int kk = 0; kk < 2; ++kk) {
      bf16x8 a = *(const bf16x8*)(ab + kk * 32 + quad * 8);
#pragma unroll
      for (int nt = 0; nt < 16; ++nt) {
        bf16x8 b = *(const bf16x8*)&Bt[(nt * 16 + l15) * 72 + kk * 32 + quad * 8];
        acc[nt] = MFMA(a, b, acc[nt]);
      }
    }
  }
  const int t0 = rb * 64 + wid * 16 + quad * 4;
#pragma unroll
  for (int nt = 0; nt < 16; ++nt) {
    const int n = nb * 256 + nt * 16 + l15;
#pragma unroll
    for (int r = 0; r < 4; ++r) {
      const float x = acc[nt][r];
      const float y = 0.5f * x * (1.f + erff(x * 0.70710678118654752f));  // exact gelu
      hid[(size_t)(t0 + r) * 1024 + n] = f2b(y);
    }
  }
}

// ---------------- kernel 5: hidden @ W2 + LN(g2,b2) + residual -> out fp32 -----------
__global__ __launch_bounds__(256, 4)
void k_mlp2(const u16* __restrict__ hid, const u16* __restrict__ w2t,
            const float* __restrict__ g2, const float* __restrict__ b2,
            const float* __restrict__ src, float* __restrict__ out) {
  const int tid = threadIdx.x, bid = blockIdx.x;
  const int lane = tid & 63, wid = tid >> 6;
  const int l15 = lane & 15, quad = lane >> 4;
  const int arow = bid * 64 + wid * 16 + l15;
  const f32x4 fz = {0.f, 0.f, 0.f, 0.f};
  f32x4 acc[8];
#pragma unroll
  for (int nt = 0; nt < 8; ++nt) acc[nt] = fz;
#pragma unroll 2
  for (int kc = 0; kc < 32; ++kc) {
    bf16x8 a = *(const bf16x8*)(hid + (size_t)arow * 1024 + kc * 32 + quad * 8);
#pragma unroll
    for (int nt = 0; nt < 8; ++nt) {
      bf16x8 b = *(const bf16x8*)(w2t + (nt * 16 + l15) * 1024 + kc * 32 + quad * 8);
      acc[nt] = MFMA(a, b, acc[nt]);
    }
  }
  float sum[4] = {0, 0, 0, 0}, sq[4] = {0, 0, 0, 0};
#pragma unroll
  for (int nt = 0; nt < 8; ++nt)
#pragma unroll
    for (int r = 0; r < 4; ++r) {
      const float v = acc[nt][r];
      sum[r] += v;
      sq[r] += v * v;
    }
#pragma unroll
  for (int off = 1; off < 16; off <<= 1)
#pragma unroll
    for (int r = 0; r < 4; ++r) {
      sum[r] += __shfl_xor(sum[r], off, 16);
      sq[r] += __shfl_xor(sq[r], off, 16);
    }
  float mean[4], rstd[4];
#pragma unroll
  for (int r = 0; r < 4; ++r) {
    mean[r] = sum[r] * (1.f / 128.f);
    const float var = sq[r] * (1.f / 128.f) - mean[r] * mean[r];
    rstd[r] = rsqrtf(var + 1e-5f);
  }
  const int t0 = bid * 64 + wid * 16 + quad * 4;
#pragma unroll
  for (int nt = 0; nt < 8; ++nt) {
    const int d = nt * 16 + l15;
    const float gg = g2[d], bb = b2[d];
#pragma unroll
    for (int r = 0; r < 4; ++r) {
      const int idx = (t0 + r) * 128 + d;
      out[idx] = src[idx] + (acc[nt][r] - mean[r]) * rstd[r] * gg + bb;
    }
  }
}

extern "C" void kernel_launch(void* const* d_in, const int* in_sizes, int n_in,
                              void* d_out, int out_size, void* d_ws, size_t ws_size,
                              hipStream_t stream) {
  const float* src  = (const float*)d_in[0];
  const float* mask = (const float*)d_in[2];
  const float* Wq = (const float*)d_in[8];
  const float* Wk = (const float*)d_in[9];
  const float* Wv = (const float*)d_in[10];
  const float* Wm = (const float*)d_in[11];
  const float* g1 = (const float*)d_in[12];
  const float* b1 = (const float*)d_in[13];
  const float* W1 = (const float*)d_in[14];
  const float* W2 = (const float*)d_in[15];
  const float* g2 = (const float*)d_in[16];
  const float* b2 = (const float*)d_in[17];
  char* ws = (char*)d_ws;
  u16* qw   = (u16*)(ws + QW_OFF);
  u16* kw   = (u16*)(ws + KW_OFF);
  u16* vbuf = (u16*)(ws + VBUF_OFF);
  float* o1 = (float*)(ws + O1_OFF);
  float* o2 = (float*)(ws + O2_OFF);
  float* l1 = (float*)(ws + L1_OFF);
  float* l2 = (float*)(ws + L2P_OFF);
  u16* hid  = (u16*)(ws + HID_OFF);
  u16* srcb = (u16*)(ws + SRCB_OFF);
  u16* msg1 = (u16*)(ws + MSG1_OFF);
  u16* wqt = (u16*)(ws + WQT_OFF);
  u16* wkt = (u16*)(ws + WKT_OFF);
  u16* wvt = (u16*)(ws + WVT_OFF);
  u16* wmt = (u16*)(ws + WMT_OFF);
  u16* w1t = (u16*)(ws + W1T_OFF);
  u16* w2t = (u16*)(ws + W2T_OFF);

  k_prep<<<1792, 256, 0, stream>>>(Wq, Wk, Wv, Wm, W1, W2, wqt, wkt, wvt, wmt, w1t, w2t);
  k_qkv<<<512, 256, 0, stream>>>(src, wqt, wkt, wvt, qw, kw, vbuf, srcb);
  k_attn<<<1024, 256, 0, stream>>>(qw, kw, vbuf, mask, o1, o2, l1, l2);
  k_wmln<<<512, 256, 0, stream>>>(o1, o2, l1, l2, wmt, g1, b1, msg1);
  k_mlp1<<<2048, 256, 0, stream>>>(srcb, msg1, w1t, hid);
  k_mlp2<<<512, 256, 0, stream>>>(hid, w2t, g2, b2, src, (float*)d_out);
}

// Round 4
// 340.956 us; speedup vs baseline: 1.2606x; 1.2606x over previous
//
#include <hip/hip_runtime.h>

typedef unsigned short u16;
typedef __bf16 bf16x8 __attribute__((ext_vector_type(8)));
typedef float f32x4 __attribute__((ext_vector_type(4)));

#define MFMA(a, b, c) __builtin_amdgcn_mfma_f32_16x16x32_bf16(a, b, c, 0, 0, 0)

// Constants: B=4, H=64, W=128, D=128, NS=2, hh=32, ww=64, sh=16, sw=32,
// L=2048, 16 windows, 32768 rows total.

__device__ __forceinline__ u16 f2b(float f) {
  unsigned u = __builtin_bit_cast(unsigned, f);
  u += 0x7fffu + ((u >> 16) & 1u);
  return (u16)(u >> 16);
}
__device__ __forceinline__ float b2f(u16 h) {
  unsigned u = (unsigned)h << 16;
  return __builtin_bit_cast(float, u);
}
__device__ __forceinline__ void glds16(const u16* g, u16* l) {
  __builtin_amdgcn_global_load_lds((const __attribute__((address_space(1))) void*)g,
                                   (__attribute__((address_space(3))) void*)l, 16, 0, 0);
}

// ---------------- workspace layout (bytes) ----------------
#define QW_OFF   ((size_t)0)
#define KW_OFF   ((size_t)8 << 20)
#define VBUF_OFF ((size_t)16 << 20)
#define O1_OFF   ((size_t)24 << 20)   // bf16 normalized partials, 8MB
#define O2_OFF   ((size_t)40 << 20)
#define HID_OFF  ((size_t)0)
#define SRCB_OFF ((size_t)64 << 20)
#define MSG1_OFF ((size_t)72 << 20)
#define L1_OFF   ((size_t)80 << 20)
#define L2P_OFF  (((size_t)80 << 20) + 131072)
#define WQT_OFF  (((size_t)80 << 20) + 262144)
#define WKT_OFF  (WQT_OFF + 32768)
#define WVT_OFF  (WQT_OFF + 65536)
#define WMT_OFF  (WQT_OFF + 98304)
#define W1T_OFF  (WQT_OFF + 131072)
#define W2T_OFF  (WQT_OFF + 655360)

// ---------------- kernel 0: transpose weights to bf16 [n][k]; scale folded into Wq ----
__global__ void k_prep(const float* __restrict__ wq, const float* __restrict__ wk,
                       const float* __restrict__ wv, const float* __restrict__ wm,
                       const float* __restrict__ w1, const float* __restrict__ w2,
                       u16* __restrict__ wqt, u16* __restrict__ wkt,
                       u16* __restrict__ wvt, u16* __restrict__ wmt,
                       u16* __restrict__ w1t, u16* __restrict__ w2t) {
  int t = blockIdx.x * 256 + threadIdx.x;
  if (t < 65536) {
    int m = t >> 14, loc = t & 16383;
    int n = loc >> 7, k = loc & 127;
    const float* s = (m == 0) ? wq : (m == 1) ? wk : (m == 2) ? wv : wm;
    u16* d = (m == 0) ? wqt : (m == 1) ? wkt : (m == 2) ? wvt : wmt;
    const float sc = (m == 0) ? 0.08838834764831845f : 1.0f;
    d[n * 128 + k] = f2b(s[k * 128 + n] * sc);
  } else if (t < 65536 + 262144) {
    int loc = t - 65536;
    int n = loc >> 8, k = loc & 255;
    w1t[n * 256 + k] = f2b(w1[k * 1024 + n]);
  } else if (t < 65536 + 262144 + 131072) {
    int loc = t - 327680;
    int n = loc >> 10, k = loc & 1023;
    w2t[n * 1024 + k] = f2b(w2[k * 128 + n]);
  }
}

// ---------------- kernel 1: QKV projection (R1-proven LDS-staged version) ------------
__global__ __launch_bounds__(256, 2)
void k_qkv(const float* __restrict__ src,
           const u16* __restrict__ wtq, const u16* __restrict__ wtk,
           const u16* __restrict__ wtv,
           u16* __restrict__ qw, u16* __restrict__ kw, u16* __restrict__ vbuf,
           u16* __restrict__ srcb) {
  __shared__ __align__(16) u16 At[64 * 136];
  __shared__ __align__(16) u16 Bt[128 * 136];
  const int tid = threadIdx.x, bid = blockIdx.x;
  const int lane = tid & 63, wid = tid >> 6;
  const int l15 = lane & 15, quad = lane >> 4;

  {  // stage A tile (64 windowed rows x 128) + write srcb at original rows
    const int row = tid >> 2, part = tid & 3;
    const int t = bid * 64 + row;
    const int g = t >> 11, p = t & 2047;
    const int b = g >> 2, wi = (g >> 1) & 1, wj = g & 1;
    const int ii = p >> 6, jj = p & 63;
    const int y = (wi * 32 + ii + 16) & 63;
    const int x = (wj * 64 + jj + 32) & 127;
    const int srow = b * 8192 + y * 128 + x;
    const float4* sp = (const float4*)(src + srow * 128) + part * 8;
    u16* lp = &At[row * 136 + part * 32];
    u16* gp = srcb + srow * 128 + part * 32;
#pragma unroll
    for (int q = 0; q < 8; ++q) {
      float4 v = sp[q];
      ushort4 h = make_ushort4(f2b(v.x), f2b(v.y), f2b(v.z), f2b(v.w));
      *(ushort4*)(lp + q * 4) = h;
      *(ushort4*)(gp + q * 4) = h;
    }
  }
  __syncthreads();

  bf16x8 afrag[4];
  const int arow = wid * 16 + l15;
#pragma unroll
  for (int kk = 0; kk < 4; ++kk)
    afrag[kk] = *(const bf16x8*)&At[arow * 136 + kk * 32 + quad * 8];

  const f32x4 fz = {0.f, 0.f, 0.f, 0.f};
#pragma unroll 1
  for (int m = 0; m < 3; ++m) {
    const u16* wp = (m == 0) ? wtq : (m == 1) ? wtk : wtv;
    {  // stage B: weight [n][k] 128x128 bf16
      const int n = tid >> 1, half = tid & 1;
      const uint4* sp = (const uint4*)(wp + n * 128 + half * 64);
      uint4* dp = (uint4*)&Bt[n * 136 + half * 64];
#pragma unroll
      for (int q = 0; q < 8; ++q) dp[q] = sp[q];
    }
    __syncthreads();
    f32x4 acc[8];
#pragma unroll
    for (int nt = 0; nt < 8; ++nt) acc[nt] = fz;
#pragma unroll
    for (int kk = 0; kk < 4; ++kk) {
#pragma unroll
      for (int nt = 0; nt < 8; ++nt) {
        bf16x8 bfr = *(const bf16x8*)&Bt[(nt * 16 + l15) * 136 + kk * 32 + quad * 8];
        acc[nt] = MFMA(afrag[kk], bfr, acc[nt]);
      }
    }
    const int t0 = bid * 64 + wid * 16 + quad * 4;
    if (m < 2) {
      u16* dst = (m == 0) ? qw : kw;
#pragma unroll
      for (int nt = 0; nt < 8; ++nt) {
        const int d = nt * 16 + l15;
#pragma unroll
        for (int r = 0; r < 4; ++r) dst[(t0 + r) * 128 + d] = f2b(acc[nt][r]);
      }
    } else {
      const int g = bid >> 5;
      const int p0 = t0 & 2047;
#pragma unroll
      for (int nt = 0; nt < 8; ++nt) {
        const int d = nt * 16 + l15;
        ushort4 hv = make_ushort4(f2b(acc[nt][0]), f2b(acc[nt][1]),
                                  f2b(acc[nt][2]), f2b(acc[nt][3]));
        *(ushort4*)&vbuf[g * 262144 + d * 2048 + p0] = hv;
      }
    }
    __syncthreads();
  }
}

// ---------------- kernel 2: attention, split-K x2, glds staging + mask prefetch ------
// bid: b=bid&3 (batch, fastest -> mask L2/L3 sharing), w=(bid>>2)&3 (window pos),
// half=(bid>>4)&1, qb=bid>>5. Writes normalized bf16 O partial + l partial.
__global__ __launch_bounds__(256, 3)
void k_attn(const u16* __restrict__ qw, const u16* __restrict__ kw,
            const u16* __restrict__ vbuf, const float* __restrict__ mask,
            u16* __restrict__ o1, u16* __restrict__ o2,
            float* __restrict__ l1, float* __restrict__ l2) {
  __shared__ __align__(16) u16 Kt[64 * 128];   // [key][d], 16B-block swizzle cb^=(key&15)
  __shared__ __align__(16) u16 Vt[128 * 64];   // [d][key], 16B-block swizzle cb^=(d&7)
  __shared__ __align__(16) u16 Pt[64 * 72];
  const int tid = threadIdx.x, bid = blockIdx.x;
  const int lane = tid & 63, wid = tid >> 6;
  const int l15 = lane & 15, quad = lane >> 4;
  const int b = bid & 3, w = (bid >> 2) & 3, half = (bid >> 4) & 1, qb = bid >> 5;
  const int g = b * 4 + w;
  const int k0 = half * 1024;
  const u16* kbase = kw + g * 262144 + k0 * 128;
  const u16* vbase = vbuf + g * 262144 + k0;
  const int qrow0 = qb * 64 + wid * 16 + quad * 4;
  const float* mlane = mask + (size_t)w * 4194304 + (size_t)qrow0 * 2048 + k0 + l15;

  // static per-lane glds source offsets (elements)
  int offk[4], offv[4];
#pragma unroll
  for (int j = 0; j < 4; ++j) {
    const int s = wid * 256 + j * 64 + lane;
    const int r = s >> 4, cbk = (s & 15) ^ (r & 15);
    offk[j] = r * 128 + cbk * 8;
    const int d = s >> 3, cbv = (s & 7) ^ (d & 7);
    offv[j] = d * 2048 + cbv * 8;
  }

  bf16x8 qfrag[4];
  {
    const u16* qp = qw + g * 262144 + (qb * 64 + wid * 16 + l15) * 128 + quad * 8;
#pragma unroll
    for (int kk = 0; kk < 4; ++kk) qfrag[kk] = *(const bf16x8*)(qp + kk * 32);
  }
  const f32x4 fz = {0.f, 0.f, 0.f, 0.f};
  f32x4 o[8];
#pragma unroll
  for (int nt = 0; nt < 8; ++nt) o[nt] = fz;
  float lr[4] = {0.f, 0.f, 0.f, 0.f};
  const float L2E = 1.4426950408889634f;

  float mpf[16];
#pragma unroll
  for (int nt = 0; nt < 4; ++nt)
#pragma unroll
    for (int r = 0; r < 4; ++r) mpf[nt * 4 + r] = mlane[r * 2048 + nt * 16];

#pragma unroll 1
  for (int kt = 0; kt < 16; ++kt) {
    __syncthreads();  // previous iteration's LDS reads done
#pragma unroll
    for (int j = 0; j < 4; ++j)
      glds16(kbase + kt * 8192 + offk[j], &Kt[wid * 2048 + j * 512]);
#pragma unroll
    for (int j = 0; j < 4; ++j)
      glds16(vbase + kt * 64 + offv[j], &Vt[wid * 2048 + j * 512]);
    float mn[16];
    if (kt < 15) {  // prefetch next iteration's mask into registers
#pragma unroll
      for (int nt = 0; nt < 4; ++nt)
#pragma unroll
        for (int r = 0; r < 4; ++r)
          mn[nt * 4 + r] = mlane[r * 2048 + (kt + 1) * 64 + nt * 16];
    }
    __syncthreads();  // vmcnt(0) drain -> tiles resident

    // S = Q K^T + mask (C-init from prefetched registers; Q pre-scaled)
    f32x4 s[4];
#pragma unroll
    for (int nt = 0; nt < 4; ++nt)
#pragma unroll
      for (int r = 0; r < 4; ++r) s[nt][r] = mpf[nt * 4 + r];
#pragma unroll
    for (int kk = 0; kk < 4; ++kk)
#pragma unroll
      for (int nt = 0; nt < 4; ++nt) {
        bf16x8 bfr = *(const bf16x8*)&Kt[(nt * 16 + l15) * 128 +
                                         (((kk * 4 + quad) ^ l15) * 8)];
        s[nt] = MFMA(qfrag[kk], bfr, s[nt]);
      }
    // fixed-max softmax: p = e^s; per-lane partial row-sums (reduced in epilogue)
#pragma unroll
    for (int nt = 0; nt < 4; ++nt)
#pragma unroll
      for (int r = 0; r < 4; ++r) {
        const float pv = exp2f(s[nt][r] * L2E);
        lr[r] += pv;
        Pt[(wid * 16 + quad * 4 + r) * 72 + nt * 16 + l15] = f2b(pv);
      }
    // O += P @ V
    bf16x8 pfrag[2];
#pragma unroll
    for (int kkp = 0; kkp < 2; ++kkp)
      pfrag[kkp] = *(const bf16x8*)&Pt[(wid * 16 + l15) * 72 + kkp * 32 + quad * 8];
#pragma unroll
    for (int nt = 0; nt < 8; ++nt)
#pragma unroll
      for (int kkp = 0; kkp < 2; ++kkp) {
        bf16x8 bfr = *(const bf16x8*)&Vt[(nt * 16 + l15) * 64 +
                                         (((kkp * 4 + quad) ^ (l15 & 7)) * 8)];
        o[nt] = MFMA(pfrag[kkp], bfr, o[nt]);
      }
    if (kt < 15) {
#pragma unroll
      for (int i = 0; i < 16; ++i) mpf[i] = mn[i];
    }
  }

  // epilogue: reduce l across the 16 lanes, normalize partial, store bf16
#pragma unroll
  for (int off = 1; off < 16; off <<= 1)
#pragma unroll
    for (int r = 0; r < 4; ++r) lr[r] += __shfl_xor(lr[r], off, 16);
  u16* op = half ? o2 : o1;
  float* lp = half ? l2 : l1;
  const int t0 = g * 2048 + qrow0;
#pragma unroll
  for (int r = 0; r < 4; ++r) {
    const float inv = 1.f / lr[r];
#pragma unroll
    for (int nt = 0; nt < 8; ++nt)
      op[(size_t)(t0 + r) * 128 + nt * 16 + l15] = f2b(o[nt][r] * inv);
    if (l15 == 0) lp[t0 + r] = lr[r];
  }
}

// ---------------- kernel 3: merge bf16 partials + @Wm + LN(g1,b1) -> msg1 (spatial) --
__global__ __launch_bounds__(256, 2)
void k_wmln(const u16* __restrict__ o1, const u16* __restrict__ o2,
            const float* __restrict__ l1, const float* __restrict__ l2,
            const u16* __restrict__ wmt, const float* __restrict__ g1,
            const float* __restrict__ b1, u16* __restrict__ msg1) {
  __shared__ __align__(16) u16 At[64 * 136];
  __shared__ __align__(16) u16 Bt[128 * 136];
  const int tid = threadIdx.x, bid = blockIdx.x;
  const int lane = tid & 63, wid = tid >> 6;
  const int l15 = lane & 15, quad = lane >> 4;
  {  // stage merged message tile: O = (l1*o1 + l2*o2)/(l1+l2)
    const int row = tid >> 2, part = tid & 3;
    const int m = bid * 64 + row;
    const float la = l1[m], lb = l2[m];
    const float wA = la / (la + lb), wB = lb / (la + lb);
    const u16* p1 = o1 + (size_t)m * 128 + part * 32;
    const u16* p2 = o2 + (size_t)m * 128 + part * 32;
    u16* lp = &At[row * 136 + part * 32];
#pragma unroll
    for (int q = 0; q < 4; ++q) {
      ushort4 xa = *(const ushort4*)(p1 + q * 8);
      ushort4 xb = *(const ushort4*)(p1 + q * 8 + 4);
      ushort4 ya = *(const ushort4*)(p2 + q * 8);
      ushort4 yb = *(const ushort4*)(p2 + q * 8 + 4);
      ushort4 ha = make_ushort4(f2b(b2f(xa.x) * wA + b2f(ya.x) * wB),
                                f2b(b2f(xa.y) * wA + b2f(ya.y) * wB),
                                f2b(b2f(xa.z) * wA + b2f(ya.z) * wB),
                                f2b(b2f(xa.w) * wA + b2f(ya.w) * wB));
      ushort4 hb = make_ushort4(f2b(b2f(xb.x) * wA + b2f(yb.x) * wB),
                                f2b(b2f(xb.y) * wA + b2f(yb.y) * wB),
                                f2b(b2f(xb.z) * wA + b2f(yb.z) * wB),
                                f2b(b2f(xb.w) * wA + b2f(yb.w) * wB));
      *(ushort4*)(lp + q * 8) = ha;
      *(ushort4*)(lp + q * 8 + 4) = hb;
    }
  }
  {
    const int n = tid >> 1, half = tid & 1;
    const uint4* sp = (const uint4*)(wmt + n * 128 + half * 64);
    uint4* dp = (uint4*)&Bt[n * 136 + half * 64];
#pragma unroll
    for (int q = 0; q < 8; ++q) dp[q] = sp[q];
  }
  __syncthreads();
  bf16x8 afrag[4];
  const int arow = wid * 16 + l15;
#pragma unroll
  for (int kk = 0; kk < 4; ++kk)
    afrag[kk] = *(const bf16x8*)&At[arow * 136 + kk * 32 + quad * 8];
  const f32x4 fz = {0.f, 0.f, 0.f, 0.f};
  f32x4 acc[8];
#pragma unroll
  for (int nt = 0; nt < 8; ++nt) acc[nt] = fz;
#pragma unroll
  for (int kk = 0; kk < 4; ++kk)
#pragma unroll
    for (int nt = 0; nt < 8; ++nt) {
      bf16x8 bfr = *(const bf16x8*)&Bt[(nt * 16 + l15) * 136 + kk * 32 + quad * 8];
      acc[nt] = MFMA(afrag[kk], bfr, acc[nt]);
    }
  float sum[4] = {0, 0, 0, 0}, sq[4] = {0, 0, 0, 0};
#pragma unroll
  for (int nt = 0; nt < 8; ++nt)
#pragma unroll
    for (int r = 0; r < 4; ++r) {
      const float v = acc[nt][r];
      sum[r] += v;
      sq[r] += v * v;
    }
#pragma unroll
  for (int off = 1; off < 16; off <<= 1)
#pragma unroll
    for (int r = 0; r < 4; ++r) {
      sum[r] += __shfl_xor(sum[r], off, 16);
      sq[r] += __shfl_xor(sq[r], off, 16);
    }
  float mean[4], rstd[4];
#pragma unroll
  for (int r = 0; r < 4; ++r) {
    mean[r] = sum[r] * (1.f / 128.f);
    const float var = sq[r] * (1.f / 128.f) - mean[r] * mean[r];
    rstd[r] = rsqrtf(var + 1e-5f);
  }
  const int t0 = bid * 64 + wid * 16 + quad * 4;
#pragma unroll
  for (int nt = 0; nt < 8; ++nt) {
    const int d = nt * 16 + l15;
    const float gg = g1[d], bb = b1[d];
#pragma unroll
    for (int r = 0; r < 4; ++r) {
      const int tt = t0 + r;                     // window-order -> spatial scatter
      const int gw = tt >> 11, pp = tt & 2047;
      const int bb2 = gw >> 2, wi = (gw >> 1) & 1, wj = gw & 1;
      const int ii = pp >> 6, jj = pp & 63;
      const int yy = (wi * 32 + ii + 16) & 63;
      const int xx = (wj * 64 + jj + 32) & 127;
      msg1[(bb2 * 8192 + yy * 128 + xx) * 128 + d] =
          f2b((acc[nt][r] - mean[r]) * rstd[r] * gg + bb);
    }
  }
}

// ---------------- kernel 4: gelu([src||msg1] @ W1) -> hidden bf16 (R1 version) -------
__global__ __launch_bounds__(256, 3)
void k_mlp1(const u16* __restrict__ srcb, const u16* __restrict__ msg1,
            const u16* __restrict__ w1t, u16* __restrict__ hid) {
  __shared__ __align__(16) u16 At[64 * 72];
  __shared__ __align__(16) u16 Bt[256 * 72];
  const int tid = threadIdx.x, bid = blockIdx.x;
  const int rb = bid >> 2, nb = bid & 3;
  const int lane = tid & 63, wid = tid >> 6;
  const int l15 = lane & 15, quad = lane >> 4;
  const f32x4 fz = {0.f, 0.f, 0.f, 0.f};
  f32x4 acc[16];
#pragma unroll
  for (int nt = 0; nt < 16; ++nt) acc[nt] = fz;
#pragma unroll 1
  for (int kc = 0; kc < 4; ++kc) {
    __syncthreads();
    {
      const int row = tid >> 2, part = tid & 3;
      const u16* sp0 = (kc < 2) ? srcb : msg1;
      const uint4* sp = (const uint4*)(sp0 + (rb * 64 + row) * 128 + (kc & 1) * 64 + part * 16);
      uint4* dp = (uint4*)&At[row * 72 + part * 16];
      dp[0] = sp[0];
      dp[1] = sp[1];
    }
    {
      const uint4* sp = (const uint4*)(w1t + (nb * 256 + tid) * 256 + kc * 64);
      uint4* dp = (uint4*)&Bt[tid * 72];
#pragma unroll
      for (int q = 0; q < 8; ++q) dp[q] = sp[q];
    }
    __syncthreads();
#pragma unroll
    for (int kk = 0; kk < 2; ++kk) {
      bf16x8 a = *(const bf16x8*)&At[(wid * 16 + l15) * 72 + kk * 32 + quad * 8];
#pragma unroll
      for (int nt = 0; nt < 16; ++nt) {
        bf16x8 b = *(const bf16x8*)&Bt[(nt * 16 + l15) * 72 + kk * 32 + quad * 8];
        acc[nt] = MFMA(a, b, acc[nt]);
      }
    }
  }
  const int t0 = rb * 64 + wid * 16 + quad * 4;
#pragma unroll
  for (int nt = 0; nt < 16; ++nt) {
    const int n = nb * 256 + nt * 16 + l15;
#pragma unroll
    for (int r = 0; r < 4; ++r) {
      const float x = acc[nt][r];
      const float y = 0.5f * x * (1.f + erff(x * 0.70710678118654752f));
      hid[(size_t)(t0 + r) * 1024 + n] = f2b(y);
    }
  }
}

// ---------------- kernel 5: hidden @ W2 + LN(g2,b2) + residual -> out fp32 (R1) ------
__global__ __launch_bounds__(256, 2)
void k_mlp2(const u16* __restrict__ hid, const u16* __restrict__ w2t,
            const float* __restrict__ g2, const float* __restrict__ b2,
            const float* __restrict__ src, float* __restrict__ out) {
  __shared__ __align__(16) u16 At[64 * 72];
  __shared__ __align__(16) u16 Bt[128 * 72];
  const int tid = threadIdx.x, bid = blockIdx.x;
  const int lane = tid & 63, wid = tid >> 6;
  const int l15 = lane & 15, quad = lane >> 4;
  const f32x4 fz = {0.f, 0.f, 0.f, 0.f};
  f32x4 acc[8];
#pragma unroll
  for (int nt = 0; nt < 8; ++nt) acc[nt] = fz;
#pragma unroll 1
  for (int kc = 0; kc < 16; ++kc) {
    __syncthreads();
    {
      const int row = tid >> 2, part = tid & 3;
      const uint4* sp = (const uint4*)(hid + (size_t)(bid * 64 + row) * 1024 + kc * 64 + part * 16);
      uint4* dp = (uint4*)&At[row * 72 + part * 16];
      dp[0] = sp[0];
      dp[1] = sp[1];
    }
    {
      const int n = tid >> 1, half = tid & 1;
      const uint4* sp = (const uint4*)(w2t + n * 1024 + kc * 64 + half * 32);
      uint4* dp = (uint4*)&Bt[n * 72 + half * 32];
#pragma unroll
      for (int q = 0; q < 4; ++q) dp[q] = sp[q];
    }
    __syncthreads();
#pragma unroll
    for (int kk = 0; kk < 2; ++kk) {
      bf16x8 a = *(const bf16x8*)&At[(wid * 16 + l15) * 72 + kk * 32 + quad * 8];
#pragma unroll
      for (int nt = 0; nt < 8; ++nt) {
        bf16x8 b = *(const bf16x8*)&Bt[(nt * 16 + l15) * 72 + kk * 32 + quad * 8];
        acc[nt] = MFMA(a, b, acc[nt]);
      }
    }
  }
  float sum[4] = {0, 0, 0, 0}, sq[4] = {0, 0, 0, 0};
#pragma unroll
  for (int nt = 0; nt < 8; ++nt)
#pragma unroll
    for (int r = 0; r < 4; ++r) {
      const float v = acc[nt][r];
      sum[r] += v;
      sq[r] += v * v;
    }
#pragma unroll
  for (int off = 1; off < 16; off <<= 1)
#pragma unroll
    for (int r = 0; r < 4; ++r) {
      sum[r] += __shfl_xor(sum[r], off, 16);
      sq[r] += __shfl_xor(sq[r], off, 16);
    }
  float mean[4], rstd[4];
#pragma unroll
  for (int r = 0; r < 4; ++r) {
    mean[r] = sum[r] * (1.f / 128.f);
    const float var = sq[r] * (1.f / 128.f) - mean[r] * mean[r];
    rstd[r] = rsqrtf(var + 1e-5f);
  }
  const int t0 = bid * 64 + wid * 16 + quad * 4;
#pragma unroll
  for (int nt = 0; nt < 8; ++nt) {
    const int d = nt * 16 + l15;
    const float gg = g2[d], bb = b2[d];
#pragma unroll
    for (int r = 0; r < 4; ++r) {
      const int idx = (t0 + r) * 128 + d;
      out[idx] = src[idx] + (acc[nt][r] - mean[r]) * rstd[r] * gg + bb;
    }
  }
}

extern "C" void kernel_launch(void* const* d_in, const int* in_sizes, int n_in,
                              void* d_out, int out_size, void* d_ws, size_t ws_size,
                              hipStream_t stream) {
  const float* src  = (const float*)d_in[0];
  const float* mask = (const float*)d_in[2];
  const float* Wq = (const float*)d_in[8];
  const float* Wk = (const float*)d_in[9];
  const float* Wv = (const float*)d_in[10];
  const float* Wm = (const float*)d_in[11];
  const float* g1 = (const float*)d_in[12];
  const float* b1 = (const float*)d_in[13];
  const float* W1 = (const float*)d_in[14];
  const float* W2 = (const float*)d_in[15];
  const float* g2 = (const float*)d_in[16];
  const float* b2 = (const float*)d_in[17];
  char* ws = (char*)d_ws;
  u16* qw   = (u16*)(ws + QW_OFF);
  u16* kw   = (u16*)(ws + KW_OFF);
  u16* vbuf = (u16*)(ws + VBUF_OFF);
  u16* o1   = (u16*)(ws + O1_OFF);
  u16* o2   = (u16*)(ws + O2_OFF);
  float* l1 = (float*)(ws + L1_OFF);
  float* l2 = (float*)(ws + L2P_OFF);
  u16* hid  = (u16*)(ws + HID_OFF);
  u16* srcb = (u16*)(ws + SRCB_OFF);
  u16* msg1 = (u16*)(ws + MSG1_OFF);
  u16* wqt = (u16*)(ws + WQT_OFF);
  u16* wkt = (u16*)(ws + WKT_OFF);
  u16* wvt = (u16*)(ws + WVT_OFF);
  u16* wmt = (u16*)(ws + WMT_OFF);
  u16* w1t = (u16*)(ws + W1T_OFF);
  u16* w2t = (u16*)(ws + W2T_OFF);

  k_prep<<<1792, 256, 0, stream>>>(Wq, Wk, Wv, Wm, W1, W2, wqt, wkt, wvt, wmt, w1t, w2t);
  k_qkv<<<512, 256, 0, stream>>>(src, wqt, wkt, wvt, qw, kw, vbuf, srcb);
  k_attn<<<1024, 256, 0, stream>>>(qw, kw, vbuf, mask, o1, o2, l1, l2);
  k_wmln<<<512, 256, 0, stream>>>(o1, o2, l1, l2, wmt, g1, b1, msg1);
  k_mlp1<<<2048, 256, 0, stream>>>(srcb, msg1, w1t, hid);
  k_mlp2<<<512, 256, 0, stream>>>(hid, w2t, g2, b2, src, (float*)d_out);
}

// Round 5
// 333.053 us; speedup vs baseline: 1.2906x; 1.0237x over previous
//
#include <hip/hip_runtime.h>

typedef unsigned short u16;
typedef __bf16 bf16x8 __attribute__((ext_vector_type(8)));
typedef float f32x4 __attribute__((ext_vector_type(4)));

#define MFMA(a, b, c) __builtin_amdgcn_mfma_f32_16x16x32_bf16(a, b, c, 0, 0, 0)

// Constants: B=4, H=64, W=128, D=128, NS=2, hh=32, ww=64, sh=16, sw=32,
// L=2048, 16 windows, 32768 rows total.

__device__ __forceinline__ u16 f2b(float f) {
  unsigned u = __builtin_bit_cast(unsigned, f);
  u += 0x7fffu + ((u >> 16) & 1u);
  return (u16)(u >> 16);
}
__device__ __forceinline__ float b2f(u16 h) {
  unsigned u = (unsigned)h << 16;
  return __builtin_bit_cast(float, u);
}
__device__ __forceinline__ void glds16(const u16* g, u16* l) {
  __builtin_amdgcn_global_load_lds((const __attribute__((address_space(1))) void*)g,
                                   (__attribute__((address_space(3))) void*)l, 16, 0, 0);
}

// ---------------- workspace layout (bytes) ----------------
#define QW_OFF   ((size_t)0)
#define KW_OFF   ((size_t)8 << 20)
#define VBUF_OFF ((size_t)16 << 20)
#define O1_OFF   ((size_t)24 << 20)   // bf16 normalized partials, 8MB
#define O2_OFF   ((size_t)40 << 20)
#define HID_OFF  ((size_t)0)
#define SRCB_OFF ((size_t)64 << 20)
#define MSG1_OFF ((size_t)72 << 20)
#define L1_OFF   ((size_t)80 << 20)
#define L2P_OFF  (((size_t)80 << 20) + 131072)
#define WQT_OFF  (((size_t)80 << 20) + 262144)
#define WKT_OFF  (WQT_OFF + 32768)
#define WVT_OFF  (WQT_OFF + 65536)
#define WMT_OFF  (WQT_OFF + 98304)
#define W1T_OFF  (WQT_OFF + 131072)
#define W2T_OFF  (WQT_OFF + 655360)

// ---------------- kernel 0: transpose weights to bf16 [n][k]; scale folded into Wq ----
__global__ void k_prep(const float* __restrict__ wq, const float* __restrict__ wk,
                       const float* __restrict__ wv, const float* __restrict__ wm,
                       const float* __restrict__ w1, const float* __restrict__ w2,
                       u16* __restrict__ wqt, u16* __restrict__ wkt,
                       u16* __restrict__ wvt, u16* __restrict__ wmt,
                       u16* __restrict__ w1t, u16* __restrict__ w2t) {
  int t = blockIdx.x * 256 + threadIdx.x;
  if (t < 65536) {
    int m = t >> 14, loc = t & 16383;
    int n = loc >> 7, k = loc & 127;
    const float* s = (m == 0) ? wq : (m == 1) ? wk : (m == 2) ? wv : wm;
    u16* d = (m == 0) ? wqt : (m == 1) ? wkt : (m == 2) ? wvt : wmt;
    const float sc = (m == 0) ? 0.08838834764831845f : 1.0f;
    d[n * 128 + k] = f2b(s[k * 128 + n] * sc);
  } else if (t < 65536 + 262144) {
    int loc = t - 65536;
    int n = loc >> 8, k = loc & 255;
    w1t[n * 256 + k] = f2b(w1[k * 1024 + n]);
  } else if (t < 65536 + 262144 + 131072) {
    int loc = t - 327680;
    int n = loc >> 10, k = loc & 1023;
    w2t[n * 1024 + k] = f2b(w2[k * 128 + n]);
  }
}

// ---------------- kernel 1: QKV projection (R1-proven LDS-staged version) ------------
__global__ __launch_bounds__(256, 2)
void k_qkv(const float* __restrict__ src,
           const u16* __restrict__ wtq, const u16* __restrict__ wtk,
           const u16* __restrict__ wtv,
           u16* __restrict__ qw, u16* __restrict__ kw, u16* __restrict__ vbuf,
           u16* __restrict__ srcb) {
  __shared__ __align__(16) u16 At[64 * 136];
  __shared__ __align__(16) u16 Bt[128 * 136];
  const int tid = threadIdx.x, bid = blockIdx.x;
  const int lane = tid & 63, wid = tid >> 6;
  const int l15 = lane & 15, quad = lane >> 4;

  {  // stage A tile (64 windowed rows x 128) + write srcb at original rows
    const int row = tid >> 2, part = tid & 3;
    const int t = bid * 64 + row;
    const int g = t >> 11, p = t & 2047;
    const int b = g >> 2, wi = (g >> 1) & 1, wj = g & 1;
    const int ii = p >> 6, jj = p & 63;
    const int y = (wi * 32 + ii + 16) & 63;
    const int x = (wj * 64 + jj + 32) & 127;
    const int srow = b * 8192 + y * 128 + x;
    const float4* sp = (const float4*)(src + srow * 128) + part * 8;
    u16* lp = &At[row * 136 + part * 32];
    u16* gp = srcb + srow * 128 + part * 32;
#pragma unroll
    for (int q = 0; q < 8; ++q) {
      float4 v = sp[q];
      ushort4 h = make_ushort4(f2b(v.x), f2b(v.y), f2b(v.z), f2b(v.w));
      *(ushort4*)(lp + q * 4) = h;
      *(ushort4*)(gp + q * 4) = h;
    }
  }
  __syncthreads();

  bf16x8 afrag[4];
  const int arow = wid * 16 + l15;
#pragma unroll
  for (int kk = 0; kk < 4; ++kk)
    afrag[kk] = *(const bf16x8*)&At[arow * 136 + kk * 32 + quad * 8];

  const f32x4 fz = {0.f, 0.f, 0.f, 0.f};
#pragma unroll 1
  for (int m = 0; m < 3; ++m) {
    const u16* wp = (m == 0) ? wtq : (m == 1) ? wtk : wtv;
    {  // stage B: weight [n][k] 128x128 bf16
      const int n = tid >> 1, half = tid & 1;
      const uint4* sp = (const uint4*)(wp + n * 128 + half * 64);
      uint4* dp = (uint4*)&Bt[n * 136 + half * 64];
#pragma unroll
      for (int q = 0; q < 8; ++q) dp[q] = sp[q];
    }
    __syncthreads();
    f32x4 acc[8];
#pragma unroll
    for (int nt = 0; nt < 8; ++nt) acc[nt] = fz;
#pragma unroll
    for (int kk = 0; kk < 4; ++kk) {
#pragma unroll
      for (int nt = 0; nt < 8; ++nt) {
        bf16x8 bfr = *(const bf16x8*)&Bt[(nt * 16 + l15) * 136 + kk * 32 + quad * 8];
        acc[nt] = MFMA(afrag[kk], bfr, acc[nt]);
      }
    }
    const int t0 = bid * 64 + wid * 16 + quad * 4;
    if (m < 2) {
      u16* dst = (m == 0) ? qw : kw;
#pragma unroll
      for (int nt = 0; nt < 8; ++nt) {
        const int d = nt * 16 + l15;
#pragma unroll
        for (int r = 0; r < 4; ++r) dst[(t0 + r) * 128 + d] = f2b(acc[nt][r]);
      }
    } else {
      const int g = bid >> 5;
      const int p0 = t0 & 2047;
#pragma unroll
      for (int nt = 0; nt < 8; ++nt) {
        const int d = nt * 16 + l15;
        ushort4 hv = make_ushort4(f2b(acc[nt][0]), f2b(acc[nt][1]),
                                  f2b(acc[nt][2]), f2b(acc[nt][3]));
        *(ushort4*)&vbuf[g * 262144 + d * 2048 + p0] = hv;
      }
    }
    __syncthreads();
  }
}

// ---------------- kernel 2: attention, dbuf glds, 32-key tiles, 1 barrier/iter -------
// bid: b=bid&3 (batch fastest -> mask L2 sharing), w=(bid>>2)&3, half=(bid>>4)&1,
// qb=bid>>5. Fixed-max softmax; normalized bf16 O partial + l partial out.
__global__ __launch_bounds__(256, 4)
void k_attn(const u16* __restrict__ qw, const u16* __restrict__ kw,
            const u16* __restrict__ vbuf, const float* __restrict__ mask,
            u16* __restrict__ o1, u16* __restrict__ o2,
            float* __restrict__ l1, float* __restrict__ l2) {
  __shared__ __align__(16) u16 Kt[2][32 * 128];  // [key][d], block swizzle cb^=(key&15)
  __shared__ __align__(16) u16 Vt[2][128 * 32];  // [d][key], block swizzle cb^=(d&3)
  __shared__ __align__(16) u16 Pt[64 * 40];      // per-wave P, stride 40
  const int tid = threadIdx.x, bid = blockIdx.x;
  const int lane = tid & 63, wid = tid >> 6;
  const int l15 = lane & 15, quad = lane >> 4;
  const int b = bid & 3, w = (bid >> 2) & 3, half = (bid >> 4) & 1, qb = bid >> 5;
  const int g = b * 4 + w;
  const int k0 = half * 1024;
  const u16* kbase = kw + g * 262144 + k0 * 128;
  const u16* vbase = vbuf + g * 262144 + k0;
  const int qrow0 = qb * 64 + wid * 16 + quad * 4;
  const float* mlane = mask + (size_t)w * 4194304 + (size_t)qrow0 * 2048 + k0 + l15;

  // glds: per-thread source offsets (elems) + wave-uniform dest bases (elems)
  int offk[2], offv[2], dstb[2];
#pragma unroll
  for (int j = 0; j < 2; ++j) {
    const int s = wid * 128 + j * 64 + lane;         // linear 16B-block id, 0..511
    const int rk = s >> 4, bk = (s & 15) ^ (rk & 15);
    offk[j] = rk * 128 + bk * 8;
    const int dv = s >> 2, bv = (s & 3) ^ (dv & 3);
    offv[j] = dv * 2048 + bv * 8;
    dstb[j] = (wid * 128 + j * 64) * 8;              // + lane*16B by hardware
  }

  bf16x8 qfrag[4];
  {
    const u16* qp = qw + g * 262144 + (qb * 64 + wid * 16 + l15) * 128 + quad * 8;
#pragma unroll
    for (int kk = 0; kk < 4; ++kk) qfrag[kk] = *(const bf16x8*)(qp + kk * 32);
  }
  const f32x4 fz = {0.f, 0.f, 0.f, 0.f};
  f32x4 o[8];
#pragma unroll
  for (int nt = 0; nt < 8; ++nt) o[nt] = fz;
  float lr[4] = {0.f, 0.f, 0.f, 0.f};
  const float L2E = 1.4426950408889634f;

  // preload tile 0 + mask 0
#pragma unroll
  for (int j = 0; j < 2; ++j) {
    glds16(kbase + offk[j], &Kt[0][dstb[j]]);
    glds16(vbase + offv[j], &Vt[0][dstb[j]]);
  }
  float mpf[8];
#pragma unroll
  for (int nt = 0; nt < 2; ++nt)
#pragma unroll
    for (int r = 0; r < 4; ++r) mpf[nt * 4 + r] = mlane[r * 2048 + nt * 16];

#pragma unroll 1
  for (int kt = 0; kt < 32; ++kt) {
    const int p = kt & 1;
    __syncthreads();  // drains glds(kt) [issued a full iter ago]; prior-iter reads done
    if (kt < 31) {    // prefetch tile kt+1 into the other buffer; overlaps this compute
      const u16* kb = kbase + (kt + 1) * 4096;
      const u16* vb = vbase + (kt + 1) * 32;
#pragma unroll
      for (int j = 0; j < 2; ++j) {
        glds16(kb + offk[j], &Kt[p ^ 1][dstb[j]]);
        glds16(vb + offv[j], &Vt[p ^ 1][dstb[j]]);
      }
    }
    float mn[8];
    if (kt < 31) {
#pragma unroll
      for (int nt = 0; nt < 2; ++nt)
#pragma unroll
        for (int r = 0; r < 4; ++r)
          mn[nt * 4 + r] = mlane[r * 2048 + (kt + 1) * 32 + nt * 16];
    }

    // S = Q K^T + mask (C-init from prefetched regs; Q pre-scaled)
    f32x4 s[2];
#pragma unroll
    for (int nt = 0; nt < 2; ++nt)
#pragma unroll
      for (int r = 0; r < 4; ++r) s[nt][r] = mpf[nt * 4 + r];
#pragma unroll
    for (int kk = 0; kk < 4; ++kk)
#pragma unroll
      for (int nt = 0; nt < 2; ++nt) {
        bf16x8 bfr = *(const bf16x8*)&Kt[p][(nt * 16 + l15) * 128 +
                                           (((kk * 4 + quad) ^ l15) * 8)];
        s[nt] = MFMA(qfrag[kk], bfr, s[nt]);
      }
    // fixed-max softmax: p = e^s; per-lane partial row-sums (reduced in epilogue)
#pragma unroll
    for (int nt = 0; nt < 2; ++nt)
#pragma unroll
      for (int r = 0; r < 4; ++r) {
        const float pv = exp2f(s[nt][r] * L2E);
        lr[r] += pv;
        Pt[(wid * 16 + quad * 4 + r) * 40 + nt * 16 + l15] = f2b(pv);
      }
    // O += P @ V (P via per-wave LDS round-trip, C-layout -> A-layout)
    bf16x8 pfrag = *(const bf16x8*)&Pt[(wid * 16 + l15) * 40 + quad * 8];
#pragma unroll
    for (int nt = 0; nt < 8; ++nt) {
      bf16x8 bfr = *(const bf16x8*)&Vt[p][(nt * 16 + l15) * 32 +
                                          ((quad ^ (l15 & 3)) * 8)];
      o[nt] = MFMA(pfrag, bfr, o[nt]);
    }
    if (kt < 31) {
#pragma unroll
      for (int i = 0; i < 8; ++i) mpf[i] = mn[i];
    }
  }

  // epilogue: reduce l across the 16 lanes, normalize partial, store bf16
#pragma unroll
  for (int off = 1; off < 16; off <<= 1)
#pragma unroll
    for (int r = 0; r < 4; ++r) lr[r] += __shfl_xor(lr[r], off, 16);
  u16* op = half ? o2 : o1;
  float* lp = half ? l2 : l1;
  const int t0 = g * 2048 + qrow0;
#pragma unroll
  for (int r = 0; r < 4; ++r) {
    const float inv = 1.f / lr[r];
#pragma unroll
    for (int nt = 0; nt < 8; ++nt)
      op[(size_t)(t0 + r) * 128 + nt * 16 + l15] = f2b(o[nt][r] * inv);
    if (l15 == 0) lp[t0 + r] = lr[r];
  }
}

// ---------------- kernel 3: merge bf16 partials + @Wm + LN(g1,b1) -> msg1 (spatial) --
__global__ __launch_bounds__(256, 2)
void k_wmln(const u16* __restrict__ o1, const u16* __restrict__ o2,
            const float* __restrict__ l1, const float* __restrict__ l2,
            const u16* __restrict__ wmt, const float* __restrict__ g1,
            const float* __restrict__ b1, u16* __restrict__ msg1) {
  __shared__ __align__(16) u16 At[64 * 136];
  __shared__ __align__(16) u16 Bt[128 * 136];
  const int tid = threadIdx.x, bid = blockIdx.x;
  const int lane = tid & 63, wid = tid >> 6;
  const int l15 = lane & 15, quad = lane >> 4;
  {  // stage merged message tile: O = (l1*o1 + l2*o2)/(l1+l2)
    const int row = tid >> 2, part = tid & 3;
    const int m = bid * 64 + row;
    const float la = l1[m], lb = l2[m];
    const float wA = la / (la + lb), wB = lb / (la + lb);
    const u16* p1 = o1 + (size_t)m * 128 + part * 32;
    const u16* p2 = o2 + (size_t)m * 128 + part * 32;
    u16* lp = &At[row * 136 + part * 32];
#pragma unroll
    for (int q = 0; q < 4; ++q) {
      ushort4 xa = *(const ushort4*)(p1 + q * 8);
      ushort4 xb = *(const ushort4*)(p1 + q * 8 + 4);
      ushort4 ya = *(const ushort4*)(p2 + q * 8);
      ushort4 yb = *(const ushort4*)(p2 + q * 8 + 4);
      ushort4 ha = make_ushort4(f2b(b2f(xa.x) * wA + b2f(ya.x) * wB),
                                f2b(b2f(xa.y) * wA + b2f(ya.y) * wB),
                                f2b(b2f(xa.z) * wA + b2f(ya.z) * wB),
                                f2b(b2f(xa.w) * wA + b2f(ya.w) * wB));
      ushort4 hb = make_ushort4(f2b(b2f(xb.x) * wA + b2f(yb.x) * wB),
                                f2b(b2f(xb.y) * wA + b2f(yb.y) * wB),
                                f2b(b2f(xb.z) * wA + b2f(yb.z) * wB),
                                f2b(b2f(xb.w) * wA + b2f(yb.w) * wB));
      *(ushort4*)(lp + q * 8) = ha;
      *(ushort4*)(lp + q * 8 + 4) = hb;
    }
  }
  {
    const int n = tid >> 1, half = tid & 1;
    const uint4* sp = (const uint4*)(wmt + n * 128 + half * 64);
    uint4* dp = (uint4*)&Bt[n * 136 + half * 64];
#pragma unroll
    for (int q = 0; q < 8; ++q) dp[q] = sp[q];
  }
  __syncthreads();
  bf16x8 afrag[4];
  const int arow = wid * 16 + l15;
#pragma unroll
  for (int kk = 0; kk < 4; ++kk)
    afrag[kk] = *(const bf16x8*)&At[arow * 136 + kk * 32 + quad * 8];
  const f32x4 fz = {0.f, 0.f, 0.f, 0.f};
  f32x4 acc[8];
#pragma unroll
  for (int nt = 0; nt < 8; ++nt) acc[nt] = fz;
#pragma unroll
  for (int kk = 0; kk < 4; ++kk)
#pragma unroll
    for (int nt = 0; nt < 8; ++nt) {
      bf16x8 bfr = *(const bf16x8*)&Bt[(nt * 16 + l15) * 136 + kk * 32 + quad * 8];
      acc[nt] = MFMA(afrag[kk], bfr, acc[nt]);
    }
  float sum[4] = {0, 0, 0, 0}, sq[4] = {0, 0, 0, 0};
#pragma unroll
  for (int nt = 0; nt < 8; ++nt)
#pragma unroll
    for (int r = 0; r < 4; ++r) {
      const float v = acc[nt][r];
      sum[r] += v;
      sq[r] += v * v;
    }
#pragma unroll
  for (int off = 1; off < 16; off <<= 1)
#pragma unroll
    for (int r = 0; r < 4; ++r) {
      sum[r] += __shfl_xor(sum[r], off, 16);
      sq[r] += __shfl_xor(sq[r], off, 16);
    }
  float mean[4], rstd[4];
#pragma unroll
  for (int r = 0; r < 4; ++r) {
    mean[r] = sum[r] * (1.f / 128.f);
    const float var = sq[r] * (1.f / 128.f) - mean[r] * mean[r];
    rstd[r] = rsqrtf(var + 1e-5f);
  }
  const int t0 = bid * 64 + wid * 16 + quad * 4;
#pragma unroll
  for (int nt = 0; nt < 8; ++nt) {
    const int d = nt * 16 + l15;
    const float gg = g1[d], bb = b1[d];
#pragma unroll
    for (int r = 0; r < 4; ++r) {
      const int tt = t0 + r;                     // window-order -> spatial scatter
      const int gw = tt >> 11, pp = tt & 2047;
      const int bb2 = gw >> 2, wi = (gw >> 1) & 1, wj = gw & 1;
      const int ii = pp >> 6, jj = pp & 63;
      const int yy = (wi * 32 + ii + 16) & 63;
      const int xx = (wj * 64 + jj + 32) & 127;
      msg1[(bb2 * 8192 + yy * 128 + xx) * 128 + d] =
          f2b((acc[nt][r] - mean[r]) * rstd[r] * gg + bb);
    }
  }
}

// ---------------- kernel 4: gelu([src||msg1] @ W1) -> hidden bf16 (R1 version) -------
__global__ __launch_bounds__(256, 3)
void k_mlp1(const u16* __restrict__ srcb, const u16* __restrict__ msg1,
            const u16* __restrict__ w1t, u16* __restrict__ hid) {
  __shared__ __align__(16) u16 At[64 * 72];
  __shared__ __align__(16) u16 Bt[256 * 72];
  const int tid = threadIdx.x, bid = blockIdx.x;
  const int rb = bid >> 2, nb = bid & 3;
  const int lane = tid & 63, wid = tid >> 6;
  const int l15 = lane & 15, quad = lane >> 4;
  const f32x4 fz = {0.f, 0.f, 0.f, 0.f};
  f32x4 acc[16];
#pragma unroll
  for (int nt = 0; nt < 16; ++nt) acc[nt] = fz;
#pragma unroll 1
  for (int kc = 0; kc < 4; ++kc) {
    __syncthreads();
    {
      const int row = tid >> 2, part = tid & 3;
      const u16* sp0 = (kc < 2) ? srcb : msg1;
      const uint4* sp = (const uint4*)(sp0 + (rb * 64 + row) * 128 + (kc & 1) * 64 + part * 16);
      uint4* dp = (uint4*)&At[row * 72 + part * 16];
      dp[0] = sp[0];
      dp[1] = sp[1];
    }
    {
      const uint4* sp = (const uint4*)(w1t + (nb * 256 + tid) * 256 + kc * 64);
      uint4* dp = (uint4*)&Bt[tid * 72];
#pragma unroll
      for (int q = 0; q < 8; ++q) dp[q] = sp[q];
    }
    __syncthreads();
#pragma unroll
    for (int kk = 0; kk < 2; ++kk) {
      bf16x8 a = *(const bf16x8*)&At[(wid * 16 + l15) * 72 + kk * 32 + quad * 8];
#pragma unroll
      for (int nt = 0; nt < 16; ++nt) {
        bf16x8 b = *(const bf16x8*)&Bt[(nt * 16 + l15) * 72 + kk * 32 + quad * 8];
        acc[nt] = MFMA(a, b, acc[nt]);
      }
    }
  }
  const int t0 = rb * 64 + wid * 16 + quad * 4;
#pragma unroll
  for (int nt = 0; nt < 16; ++nt) {
    const int n = nb * 256 + nt * 16 + l15;
#pragma unroll
    for (int r = 0; r < 4; ++r) {
      const float x = acc[nt][r];
      const float y = 0.5f * x * (1.f + erff(x * 0.70710678118654752f));
      hid[(size_t)(t0 + r) * 1024 + n] = f2b(y);
    }
  }
}

// ---------------- kernel 5: hidden @ W2 + LN(g2,b2) + residual -> out fp32 (R1) ------
__global__ __launch_bounds__(256, 2)
void k_mlp2(const u16* __restrict__ hid, const u16* __restrict__ w2t,
            const float* __restrict__ g2, const float* __restrict__ b2,
            const float* __restrict__ src, float* __restrict__ out) {
  __shared__ __align__(16) u16 At[64 * 72];
  __shared__ __align__(16) u16 Bt[128 * 72];
  const int tid = threadIdx.x, bid = blockIdx.x;
  const int lane = tid & 63, wid = tid >> 6;
  const int l15 = lane & 15, quad = lane >> 4;
  const f32x4 fz = {0.f, 0.f, 0.f, 0.f};
  f32x4 acc[8];
#pragma unroll
  for (int nt = 0; nt < 8; ++nt) acc[nt] = fz;
#pragma unroll 1
  for (int kc = 0; kc < 16; ++kc) {
    __syncthreads();
    {
      const int row = tid >> 2, part = tid & 3;
      const uint4* sp = (const uint4*)(hid + (size_t)(bid * 64 + row) * 1024 + kc * 64 + part * 16);
      uint4* dp = (uint4*)&At[row * 72 + part * 16];
      dp[0] = sp[0];
      dp[1] = sp[1];
    }
    {
      const int n = tid >> 1, half = tid & 1;
      const uint4* sp = (const uint4*)(w2t + n * 1024 + kc * 64 + half * 32);
      uint4* dp = (uint4*)&Bt[n * 72 + half * 32];
#pragma unroll
      for (int q = 0; q < 4; ++q) dp[q] = sp[q];
    }
    __syncthreads();
#pragma unroll
    for (int kk = 0; kk < 2; ++kk) {
      bf16x8 a = *(const bf16x8*)&At[(wid * 16 + l15) * 72 + kk * 32 + quad * 8];
#pragma unroll
      for (int nt = 0; nt < 8; ++nt) {
        bf16x8 b = *(const bf16x8*)&Bt[(nt * 16 + l15) * 72 + kk * 32 + quad * 8];
        acc[nt] = MFMA(a, b, acc[nt]);
      }
    }
  }
  float sum[4] = {0, 0, 0, 0}, sq[4] = {0, 0, 0, 0};
#pragma unroll
  for (int nt = 0; nt < 8; ++nt)
#pragma unroll
    for (int r = 0; r < 4; ++r) {
      const float v = acc[nt][r];
      sum[r] += v;
      sq[r] += v * v;
    }
#pragma unroll
  for (int off = 1; off < 16; off <<= 1)
#pragma unroll
    for (int r = 0; r < 4; ++r) {
      sum[r] += __shfl_xor(sum[r], off, 16);
      sq[r] += __shfl_xor(sq[r], off, 16);
    }
  float mean[4], rstd[4];
#pragma unroll
  for (int r = 0; r < 4; ++r) {
    mean[r] = sum[r] * (1.f / 128.f);
    const float var = sq[r] * (1.f / 128.f) - mean[r] * mean[r];
    rstd[r] = rsqrtf(var + 1e-5f);
  }
  const int t0 = bid * 64 + wid * 16 + quad * 4;
#pragma unroll
  for (int nt = 0; nt < 8; ++nt) {
    const int d = nt * 16 + l15;
    const float gg = g2[d], bb = b2[d];
#pragma unroll
    for (int r = 0; r < 4; ++r) {
      const int idx = (t0 + r) * 128 + d;
      out[idx] = src[idx] + (acc[nt][r] - mean[r]) * rstd[r] * gg + bb;
    }
  }
}

extern "C" void kernel_launch(void* const* d_in, const int* in_sizes, int n_in,
                              void* d_out, int out_size, void* d_ws, size_t ws_size,
                              hipStream_t stream) {
  const float* src  = (const float*)d_in[0];
  const float* mask = (const float*)d_in[2];
  const float* Wq = (const float*)d_in[8];
  const float* Wk = (const float*)d_in[9];
  const float* Wv = (const float*)d_in[10];
  const float* Wm = (const float*)d_in[11];
  const float* g1 = (const float*)d_in[12];
  const float* b1 = (const float*)d_in[13];
  const float* W1 = (const float*)d_in[14];
  const float* W2 = (const float*)d_in[15];
  const float* g2 = (const float*)d_in[16];
  const float* b2 = (const float*)d_in[17];
  char* ws = (char*)d_ws;
  u16* qw   = (u16*)(ws + QW_OFF);
  u16* kw   = (u16*)(ws + KW_OFF);
  u16* vbuf = (u16*)(ws + VBUF_OFF);
  u16* o1   = (u16*)(ws + O1_OFF);
  u16* o2   = (u16*)(ws + O2_OFF);
  float* l1 = (float*)(ws + L1_OFF);
  float* l2 = (float*)(ws + L2P_OFF);
  u16* hid  = (u16*)(ws + HID_OFF);
  u16* srcb = (u16*)(ws + SRCB_OFF);
  u16* msg1 = (u16*)(ws + MSG1_OFF);
  u16* wqt = (u16*)(ws + WQT_OFF);
  u16* wkt = (u16*)(ws + WKT_OFF);
  u16* wvt = (u16*)(ws + WVT_OFF);
  u16* wmt = (u16*)(ws + WMT_OFF);
  u16* w1t = (u16*)(ws + W1T_OFF);
  u16* w2t = (u16*)(ws + W2T_OFF);

  k_prep<<<1792, 256, 0, stream>>>(Wq, Wk, Wv, Wm, W1, W2, wqt, wkt, wvt, wmt, w1t, w2t);
  k_qkv<<<512, 256, 0, stream>>>(src, wqt, wkt, wvt, qw, kw, vbuf, srcb);
  k_attn<<<1024, 256, 0, stream>>>(qw, kw, vbuf, mask, o1, o2, l1, l2);
  k_wmln<<<512, 256, 0, stream>>>(o1, o2, l1, l2, wmt, g1, b1, msg1);
  k_mlp1<<<2048, 256, 0, stream>>>(srcb, msg1, w1t, hid);
  k_mlp2<<<512, 256, 0, stream>>>(hid, w2t, g2, b2, src, (float*)d_out);
}